// Round 7
// baseline (64.900 us; speedup 1.0000x reference)
//
#include <hip/hip_runtime.h>

// RBF layer: out[b,n] = exp(-GAMMA * (||x_b||^2 + ||w_n||^2 - 2 x_b . w_n))
// x: (4096,256) fp32; W: (256,512) fp32; out: (4096,512) fp32.
// TLP experiment: 512 threads/block (8 waves), 64x64 tile, wave = 32x16 out.
// 16 waves/CU (4/SIMD) to hide cache-cold load latency (ws-poison fill
// flushes L2 before every replay). Stage+norm merged, one barrier, W scalar
// from global (L2-hot after first touch), ||w||^2 in-register.

#define GAMMA 0.5f
#define B_  4096
#define D_  256
#define N_  512
#define BM  64
#define BN  64
#define LDT 264   // 256 + 8 pad (bf16): 528B row stride -> 4-bank row shift

typedef __attribute__((ext_vector_type(8))) short bf16x8;
typedef __attribute__((ext_vector_type(4))) float f32x4;
typedef __attribute__((ext_vector_type(4))) float float4v;

__device__ __forceinline__ unsigned short f2bf(float f) {
    union { float f; unsigned int i; } u; u.f = f;
    return (unsigned short)(u.i >> 16);
}

__global__ __launch_bounds__(512, 4)
void rbf_kernel(const float* __restrict__ x, const float* __restrict__ W,
                float* __restrict__ out) {
    __shared__ unsigned short xs[BM][LDT];
    __shared__ float x2s[BM];

    const int tid = threadIdx.x;

    // XCD-chunked bijective swizzle (512 % 8 == 0): XCD k owns by in [8k,8k+8)
    const int bid = blockIdx.x;
    const int wgid = (bid & 7) * 64 + (bid >> 3);
    const int bx = wgid & 7;    // 0..7
    const int by = wgid >> 3;   // 0..63

    // ---- merged stage + norm: thread (row, q) owns 32 floats of one row ----
    {
        const int row = tid >> 3, q = tid & 7;
        const float* xp = x + (size_t)(by * BM + row) * D_ + q * 32;
        unsigned short* lp = &xs[row][q * 32];
        float s = 0.f;
        #pragma unroll
        for (int c = 0; c < 4; ++c) {
            float4v v0 = *(const float4v*)(xp + c * 8);
            float4v v1 = *(const float4v*)(xp + c * 8 + 4);
            s += v0.x*v0.x + v0.y*v0.y + v0.z*v0.z + v0.w*v0.w
               + v1.x*v1.x + v1.y*v1.y + v1.z*v1.z + v1.w*v1.w;
            bf16x8 o = { (short)f2bf(v0.x), (short)f2bf(v0.y), (short)f2bf(v0.z), (short)f2bf(v0.w),
                         (short)f2bf(v1.x), (short)f2bf(v1.y), (short)f2bf(v1.z), (short)f2bf(v1.w) };
            *(bf16x8*)(lp + c * 8) = o;
        }
        s += __shfl_xor(s, 1);
        s += __shfl_xor(s, 2);
        s += __shfl_xor(s, 4);
        if (q == 0) x2s[row] = s;
    }
    __syncthreads();   // the only barrier

    // ---- MFMA: 8 waves in 2x4; each wave 32 rows x 16 cols (2 row-frags) ----
    const int l = tid & 63, w = tid >> 6;
    const int wr = w >> 2, wc = w & 3;     // wr: row half, wc: col quarter
    const int lr = l & 15, g = l >> 4;

    const float* Wg = W + bx * BN + wc * 16 + lr;   // this lane's column
    float w2p = 0.f;
    f32x4 acc0 = {0,0,0,0}, acc1 = {0,0,0,0};

    #pragma unroll
    for (int kk = 0; kk < 8; ++kk) {
        const int k0 = kk * 32 + g * 8;
        const float* wp = Wg + (size_t)k0 * N_;
        float w0[8];
        #pragma unroll
        for (int j = 0; j < 8; ++j) w0[j] = wp[(size_t)j * N_];
        bf16x8 b0;
        #pragma unroll
        for (int j = 0; j < 8; ++j) {
            b0[j] = (short)f2bf(w0[j]);
            w2p += w0[j] * w0[j];
        }
        bf16x8 a0 = *(const bf16x8*)&xs[wr * 32 + lr][k0];
        bf16x8 a1 = *(const bf16x8*)&xs[wr * 32 + 16 + lr][k0];
        acc0 = __builtin_amdgcn_mfma_f32_16x16x32_bf16(a0, b0, acc0, 0, 0, 0);
        acc1 = __builtin_amdgcn_mfma_f32_16x16x32_bf16(a1, b0, acc1, 0, 0, 0);
    }

    // w2 partial covered k = g*8..g*8+7 (+32/kk): reduce across g (^16, ^32)
    w2p += __shfl_xor(w2p, 16);
    w2p += __shfl_xor(w2p, 32);

    // ---- epilogue: C/D layout col=lane&15, row=(lane>>4)*4+i (m89/m91) ----
    const float c2l = -(GAMMA) * 1.4426950408889634f;
    float* outp = out + (size_t)(by * BM) * N_ + bx * BN;
    const int ac = wc * 16 + lr;
    #pragma unroll
    for (int m = 0; m < 2; ++m) {
        const f32x4 a = m ? acc1 : acc0;
        #pragma unroll
        for (int i = 0; i < 4; ++i) {
            const int ar = wr * 32 + m * 16 + g * 4 + i;
            const float s = x2s[ar] + w2p - 2.f * a[i];
            outp[(size_t)ar * N_ + ac] = exp2f(s * c2l);
        }
    }
}

extern "C" void kernel_launch(void* const* d_in, const int* in_sizes, int n_in,
                              void* d_out, int out_size, void* d_ws, size_t ws_size,
                              hipStream_t stream) {
    const float* x = (const float*)d_in[0];
    const float* W = (const float*)d_in[1];
    float* out = (float*)d_out;
    rbf_kernel<<<dim3(512), dim3(512), 0, stream>>>(x, W, out);
}